// Round 2
// baseline (2278.564 us; speedup 1.0000x reference)
//
#include <hip/hip_runtime.h>
#include <math.h>

#define B_   256
#define DIM_ 1024
#define H_   8
#define D_   128
#define P_   2048
#define HD_  1024

__device__ __forceinline__ float sigf(float x) { return 1.f / (1.f + expf(-x)); }

// ---------------- LayerNorm: one block per row of [256,1024] ----------------
__global__ void ln_kernel(const float* __restrict__ x, const float* __restrict__ g,
                          const float* __restrict__ bt, float* __restrict__ y) {
    int b = blockIdx.x, t = threadIdx.x;
    const float* row = x + (size_t)b * DIM_;
    float4 v = *(const float4*)(row + t * 4);
    float s1 = v.x + v.y + v.z + v.w;
    float s2 = v.x * v.x + v.y * v.y + v.z * v.z + v.w * v.w;
    #pragma unroll
    for (int o = 32; o; o >>= 1) { s1 += __shfl_down(s1, o, 64); s2 += __shfl_down(s2, o, 64); }
    __shared__ float r1[4], r2[4];
    __shared__ float mu_s, rs_s;
    int wid = t >> 6, lane = t & 63;
    if (lane == 0) { r1[wid] = s1; r2[wid] = s2; }
    __syncthreads();
    if (t == 0) {
        float S1 = r1[0] + r1[1] + r1[2] + r1[3];
        float S2 = r2[0] + r2[1] + r2[2] + r2[3];
        float mu = S1 / DIM_;
        mu_s = mu;
        rs_s = rsqrtf(S2 / DIM_ - mu * mu + 1e-5f);
    }
    __syncthreads();
    float mu = mu_s, rs = rs_s;
    float4 gg = *(const float4*)(g + t * 4);
    float4 bb = *(const float4*)(bt + t * 4);
    float4 o4;
    o4.x = (v.x - mu) * rs * gg.x + bb.x;
    o4.y = (v.y - mu) * rs * gg.y + bb.y;
    o4.z = (v.z - mu) * rs * gg.z + bb.z;
    o4.w = (v.w - mu) * rs * gg.w + bb.w;
    *(float4*)(y + (size_t)b * DIM_ + t * 4) = o4;
}

// ---------------- Generic f32 GEMM: C[M,N] = A[M,K] @ W[N,K]^T (+bias, epilogue) ----
enum { EPI_NONE = 0, EPI_SILU, EPI_SIGMOID, EPI_SCALE, EPI_RES };

template <int EPI>
__global__ void gemm_k(const float* __restrict__ A, const float* __restrict__ W,
                       const float* __restrict__ bias, float* __restrict__ C,
                       int M, int N, int K, float scale, const float* __restrict__ res) {
    __shared__ __align__(16) float As[16][65];
    __shared__ __align__(16) float Ws[16][68];
    int bm = blockIdx.y << 6, bn = blockIdx.x << 6;
    int t = threadIdx.x;
    int tx = t & 15, ty = t >> 4;
    int lr = t >> 4, lk = t & 15;
    float acc[4][4] = {};
    for (int k0 = 0; k0 < K; k0 += 16) {
        #pragma unroll
        for (int j = 0; j < 4; j++) {
            int m = lr + j * 16;
            As[lk][m] = A[(size_t)(bm + m) * K + k0 + lk];
            int n = bn + lr + j * 16;
            Ws[lk][lr + j * 16] = (n < N) ? W[(size_t)n * K + k0 + lk] : 0.f;
        }
        __syncthreads();
        #pragma unroll
        for (int k = 0; k < 16; k++) {
            float4 w4 = *(const float4*)&Ws[k][tx << 2];
            float a0 = As[k][ty], a1 = As[k][ty + 16], a2 = As[k][ty + 32], a3 = As[k][ty + 48];
            acc[0][0] = fmaf(a0, w4.x, acc[0][0]); acc[0][1] = fmaf(a0, w4.y, acc[0][1]);
            acc[0][2] = fmaf(a0, w4.z, acc[0][2]); acc[0][3] = fmaf(a0, w4.w, acc[0][3]);
            acc[1][0] = fmaf(a1, w4.x, acc[1][0]); acc[1][1] = fmaf(a1, w4.y, acc[1][1]);
            acc[1][2] = fmaf(a1, w4.z, acc[1][2]); acc[1][3] = fmaf(a1, w4.w, acc[1][3]);
            acc[2][0] = fmaf(a2, w4.x, acc[2][0]); acc[2][1] = fmaf(a2, w4.y, acc[2][1]);
            acc[2][2] = fmaf(a2, w4.z, acc[2][2]); acc[2][3] = fmaf(a2, w4.w, acc[2][3]);
            acc[3][0] = fmaf(a3, w4.x, acc[3][0]); acc[3][1] = fmaf(a3, w4.y, acc[3][1]);
            acc[3][2] = fmaf(a3, w4.z, acc[3][2]); acc[3][3] = fmaf(a3, w4.w, acc[3][3]);
        }
        __syncthreads();
    }
    int n0 = bn + (tx << 2);
    if (n0 < N) {
        float4 bv4 = make_float4(0.f, 0.f, 0.f, 0.f);
        if (bias) bv4 = *(const float4*)(bias + n0);
        #pragma unroll
        for (int r = 0; r < 4; r++) {
            int m = bm + ty + (r << 4);
            float4 o4;
            o4.x = acc[r][0] + bv4.x;
            o4.y = acc[r][1] + bv4.y;
            o4.z = acc[r][2] + bv4.z;
            o4.w = acc[r][3] + bv4.w;
            if (EPI == EPI_SILU) {
                o4.x *= sigf(o4.x); o4.y *= sigf(o4.y); o4.z *= sigf(o4.z); o4.w *= sigf(o4.w);
            } else if (EPI == EPI_SIGMOID) {
                o4.x = sigf(o4.x); o4.y = sigf(o4.y); o4.z = sigf(o4.z); o4.w = sigf(o4.w);
            } else if (EPI == EPI_SCALE) {
                o4.x *= scale; o4.y *= scale; o4.z *= scale; o4.w *= scale;
            } else if (EPI == EPI_RES) {
                float4 r4 = *(const float4*)(res + (size_t)m * N + n0);
                o4.x += r4.x; o4.y += r4.y; o4.z += r4.z; o4.w += r4.w;
            }
            *(float4*)(C + (size_t)m * N + n0) = o4;
        }
    }
}

// ---------------- Causal feature conv (KER=4) + SiLU ----------------
__global__ void conv_silu_kernel(const float* __restrict__ x_t, const float* __restrict__ w,
                                 const float* __restrict__ cb, float* __restrict__ x_c) {
    int idx = blockIdx.x * 256 + threadIdx.x;  // 0..524287
    int b = idx >> 11, p = idx & 2047;
    const float* row = x_t + (size_t)b * P_;
    float acc = cb[0];
    #pragma unroll
    for (int j = 0; j < 4; j++) {
        int pp = p - 3 + j;
        if (pp >= 0) acc = fmaf(w[j], row[pp], acc);
    }
    x_c[idx] = acc * (1.f / (1.f + expf(-acc)));
}

// ---------------- Fused cell: c/n/m update, q-readout, groupnorm, skip, r-gate ------
__global__ void cell_kernel(const float* __restrict__ q, const float* __restrict__ k,
                            const float* __restrict__ v, const float* __restrict__ o,
                            const float* __restrict__ i_t, const float* __restrict__ f_t,
                            const float* __restrict__ m_tm1, const float* __restrict__ n_tm1,
                            const float* __restrict__ c_tm1,
                            const float* __restrict__ gn_g, const float* __restrict__ gn_b,
                            const float* __restrict__ skip, const float* __restrict__ sr,
                            float* __restrict__ c_out, float* __restrict__ n_out,
                            float* __restrict__ m_out, float* __restrict__ y) {
    int bh = blockIdx.x;  // 0..2047
    int h = bh & 7;
    int t = threadIdx.x;
    __shared__ __align__(16) float qs[128];
    __shared__ __align__(16) float ks[128];
    __shared__ __align__(16) float vs[128];
    __shared__ float hnum[128];
    __shared__ float redA[4], redB[4];
    __shared__ float dsh, mu_s, rs_s;

    float fi = i_t[bh], ff = f_t[bh], mo = m_tm1[bh];
    float mt = fmaxf(ff + mo, fi);
    float ie = expf(fi - mt);
    float fe = expf(ff - mt + mo);
    if (t == 0) m_out[bh] = mt;

    int base = bh << 7;
    if (t < 128) { qs[t] = q[base + t]; ks[t] = k[base + t]; vs[t] = v[base + t]; }
    __syncthreads();

    // n_t and denominator
    float dn = 0.f;
    if (t < 128) {
        float nt = fe * n_tm1[base + t] + ie * ks[t];
        n_out[base + t] = nt;
        dn = nt * qs[t];
    }
    #pragma unroll
    for (int off2 = 32; off2; off2 >>= 1) dn += __shfl_down(dn, off2, 64);
    int wid = t >> 6, lane = t & 63;
    if (lane == 0) redA[wid] = dn;
    __syncthreads();
    if (t == 0) dsh = fmaxf(redA[0] + redA[1], 1.f);

    // c update + per-row dot with q. 8 groups of 32 lanes; each group does one row/iter.
    const float* cin = c_tm1 + ((size_t)bh << 14);
    float* cout = c_out + ((size_t)bh << 14);
    int l32 = t & 31, grp = t >> 5;
    float4 k4 = *(const float4*)&ks[l32 << 2];
    float4 q4 = *(const float4*)&qs[l32 << 2];
    #pragma unroll
    for (int it2 = 0; it2 < 16; ++it2) {
        int d = (it2 << 3) + grp;
        float vd = vs[d] * ie;
        int off = (d << 7) + (l32 << 2);
        float4 c4 = *(const float4*)(cin + off);
        float4 ct;
        ct.x = fmaf(fe, c4.x, vd * k4.x);
        ct.y = fmaf(fe, c4.y, vd * k4.y);
        ct.z = fmaf(fe, c4.z, vd * k4.z);
        ct.w = fmaf(fe, c4.w, vd * k4.w);
        *(float4*)(cout + off) = ct;
        float p = ct.x * q4.x + ct.y * q4.y + ct.z * q4.z + ct.w * q4.w;
        #pragma unroll
        for (int o2 = 16; o2; o2 >>= 1) p += __shfl_xor(p, o2, 32);
        if (l32 == 0) hnum[d] = p;
    }
    __syncthreads();

    // h, groupnorm over 128, skip add, r-gate
    float hval = 0.f;
    if (t < 128) hval = o[base + t] * hnum[t] / dsh;
    float s1 = hval, s2 = hval * hval;
    #pragma unroll
    for (int off2 = 32; off2; off2 >>= 1) { s1 += __shfl_down(s1, off2, 64); s2 += __shfl_down(s2, off2, 64); }
    if (lane == 0) { redA[wid] = s1; redB[wid] = s2; }
    __syncthreads();
    if (t == 0) {
        float S1 = redA[0] + redA[1], S2 = redB[0] + redB[1];
        float mu = S1 / 128.f;
        mu_s = mu;
        rs_s = rsqrtf(S2 / 128.f - mu * mu + 1e-5f);
    }
    __syncthreads();
    if (t < 128) {
        float xn = (hval - mu_s) * rs_s;
        int gi = (h << 7) + t;
        y[base + t] = (xn * gn_g[gi] + gn_b[gi] + skip[base + t]) * sr[base + t];
    }
}

extern "C" void kernel_launch(void* const* d_in, const int* in_sizes, int n_in,
                              void* d_out, int out_size, void* d_ws, size_t ws_size,
                              hipStream_t stream) {
    const float* seq    = (const float*)d_in[0];
    const float* c_tm1  = (const float*)d_in[1];
    const float* n_tm1  = (const float*)d_in[2];
    const float* m_tm1  = (const float*)d_in[3];
    const float* ln_g   = (const float*)d_in[4];
    const float* ln_b   = (const float*)d_in[5];
    const float* Wul    = (const float*)d_in[6];
    const float* bul    = (const float*)d_in[7];
    const float* Wur    = (const float*)d_in[8];
    const float* bur    = (const float*)d_in[9];
    const float* conv_w = (const float*)d_in[10];
    const float* conv_b = (const float*)d_in[11];
    const float* Wskip  = (const float*)d_in[12];
    const float* Wi     = (const float*)d_in[13];
    const float* bi     = (const float*)d_in[14];
    const float* Wf     = (const float*)d_in[15];
    const float* bf     = (const float*)d_in[16];
    const float* Wo     = (const float*)d_in[17];
    const float* bo     = (const float*)d_in[18];
    const float* Wq     = (const float*)d_in[19];
    const float* bq     = (const float*)d_in[20];
    const float* Wk     = (const float*)d_in[21];
    const float* bk     = (const float*)d_in[22];
    const float* Wv     = (const float*)d_in[23];
    const float* bv     = (const float*)d_in[24];
    const float* gn_g   = (const float*)d_in[25];
    const float* gn_b   = (const float*)d_in[26];
    const float* Wd     = (const float*)d_in[27];
    const float* bd     = (const float*)d_in[28];

    float* out   = (float*)d_out;          // [256,1024]
    float* c_out = out + 262144;           // [256,8,128,128]
    float* n_out = c_out + 33554432;       // [256,8,128]
    float* m_out = n_out + 262144;         // [256,8]

    float* ws    = (float*)d_ws;
    float* x_n   = ws;                  // 262144
    float* x_t   = x_n + 262144;        // 524288
    float* sr    = x_t + 524288;        // 262144 (silu(r_t))
    float* x_c   = sr + 262144;         // 524288
    float* qb    = x_c + 524288;        // 262144
    float* kb    = qb + 262144;         // 262144
    float* vb    = kb + 262144;         // 262144
    float* ob    = vb + 262144;         // 262144
    float* itb   = ob + 262144;         // 2048
    float* ftb   = itb + 2048;          // 2048
    float* skipb = ftb + 2048;          // 262144
    float* yb    = skipb + 262144;      // 262144

    dim3 blk(256);
    const float kscale = 0.088388347648318447f;  // 1/sqrt(128)

    ln_kernel<<<256, blk, 0, stream>>>(seq, ln_g, ln_b, x_n);
    gemm_k<EPI_NONE   ><<<dim3(32, 4), blk, 0, stream>>>(x_n, Wul, bul, x_t, 256, 2048, 1024, 1.f, nullptr);
    gemm_k<EPI_SILU   ><<<dim3(16, 4), blk, 0, stream>>>(x_n, Wur, bur, sr, 256, 1024, 1024, 1.f, nullptr);
    conv_silu_kernel<<<2048, blk, 0, stream>>>(x_t, conv_w, conv_b, x_c);
    gemm_k<EPI_NONE   ><<<dim3(16, 4), blk, 0, stream>>>(x_c, Wq, bq, qb, 256, 1024, 2048, 1.f, nullptr);
    gemm_k<EPI_SCALE  ><<<dim3(16, 4), blk, 0, stream>>>(x_c, Wk, bk, kb, 256, 1024, 2048, kscale, nullptr);
    gemm_k<EPI_NONE   ><<<dim3(16, 4), blk, 0, stream>>>(x_t, Wv, bv, vb, 256, 1024, 2048, 1.f, nullptr);
    gemm_k<EPI_SIGMOID><<<dim3(16, 4), blk, 0, stream>>>(x_t, Wo, bo, ob, 256, 1024, 2048, 1.f, nullptr);
    gemm_k<EPI_NONE   ><<<dim3(1, 4),  blk, 0, stream>>>(x_c, Wi, bi, itb, 256, 8, 2048, 1.f, nullptr);
    gemm_k<EPI_NONE   ><<<dim3(1, 4),  blk, 0, stream>>>(x_c, Wf, bf, ftb, 256, 8, 2048, 1.f, nullptr);
    gemm_k<EPI_NONE   ><<<dim3(16, 4), blk, 0, stream>>>(x_c, Wskip, nullptr, skipb, 256, 1024, 2048, 1.f, nullptr);
    cell_kernel<<<2048, blk, 0, stream>>>(qb, kb, vb, ob, itb, ftb, m_tm1, n_tm1, c_tm1,
                                          gn_g, gn_b, skipb, sr, c_out, n_out, m_out, yb);
    gemm_k<EPI_RES    ><<<dim3(16, 4), blk, 0, stream>>>(yb, Wd, bd, out, 256, 1024, 1024, 1.f, seq);
}

// Round 4
// 526.839 us; speedup vs baseline: 4.3250x; 4.3250x over previous
//
#include <hip/hip_runtime.h>
#include <hip/hip_bf16.h>
#include <math.h>

#define B_   256
#define DIM_ 1024
#define H_   8
#define D_   128
#define P_   2048
#define HD_  1024

typedef short short8 __attribute__((ext_vector_type(8)));
typedef float f32x4 __attribute__((ext_vector_type(4)));

__device__ __forceinline__ float sigf(float x) { return 1.f / (1.f + expf(-x)); }

__device__ __forceinline__ ushort f2bf(float f) {
    return __builtin_bit_cast(unsigned short, __float2bfloat16(f));
}
__device__ __forceinline__ float bf2f(ushort u) {
    unsigned int v = ((unsigned int)u) << 16;
    return __builtin_bit_cast(float, v);
}

// ---------------- LayerNorm -> bf16: one block per row of [256,1024] ----------------
__global__ void ln_kernel(const float* __restrict__ x, const float* __restrict__ g,
                          const float* __restrict__ bt, ushort* __restrict__ y) {
    int b = blockIdx.x, t = threadIdx.x;
    const float* row = x + (size_t)b * DIM_;
    float4 v = *(const float4*)(row + t * 4);
    float s1 = v.x + v.y + v.z + v.w;
    float s2 = v.x * v.x + v.y * v.y + v.z * v.z + v.w * v.w;
    #pragma unroll
    for (int o = 32; o; o >>= 1) { s1 += __shfl_down(s1, o, 64); s2 += __shfl_down(s2, o, 64); }
    __shared__ float r1[4], r2[4];
    __shared__ float mu_s, rs_s;
    int wid = t >> 6, lane = t & 63;
    if (lane == 0) { r1[wid] = s1; r2[wid] = s2; }
    __syncthreads();
    if (t == 0) {
        float S1 = r1[0] + r1[1] + r1[2] + r1[3];
        float S2 = r2[0] + r2[1] + r2[2] + r2[3];
        float mu = S1 / DIM_;
        mu_s = mu;
        rs_s = rsqrtf(S2 / DIM_ - mu * mu + 1e-5f);
    }
    __syncthreads();
    float mu = mu_s, rs = rs_s;
    float4 gg = *(const float4*)(g + t * 4);
    float4 bb = *(const float4*)(bt + t * 4);
    ushort4 o4;
    o4.x = f2bf((v.x - mu) * rs * gg.x + bb.x);
    o4.y = f2bf((v.y - mu) * rs * gg.y + bb.y);
    o4.z = f2bf((v.z - mu) * rs * gg.z + bb.z);
    o4.w = f2bf((v.w - mu) * rs * gg.w + bb.w);
    *(ushort4*)(y + (size_t)b * DIM_ + t * 4) = o4;
}

// ---------------- MFMA GEMM: C[256,N] = A_bf16[256,K] @ W_f32[N,K]^T, segmented N ----
// Register-only (no LDS): each lane loads its fragment directly (8 contiguous K elems).
// Wave layout: 4 waves (2x2), each wave 32x32 out, block tile 64x64.
__device__ __forceinline__ short8 cvtW8(const float* __restrict__ p) {
    f32x4 x = *(const f32x4*)p;
    f32x4 y = *(const f32x4*)(p + 4);
    short8 r;
    r[0] = (short)f2bf(x[0]); r[1] = (short)f2bf(x[1]);
    r[2] = (short)f2bf(x[2]); r[3] = (short)f2bf(x[3]);
    r[4] = (short)f2bf(y[0]); r[5] = (short)f2bf(y[1]);
    r[6] = (short)f2bf(y[2]); r[7] = (short)f2bf(y[3]);
    return r;
}

template <int LID>
__global__ void mgemm(const ushort* __restrict__ A,
                      const float* __restrict__ W0, const float* __restrict__ W1,
                      const float* __restrict__ W2,
                      const float* __restrict__ b0, const float* __restrict__ b1,
                      const float* __restrict__ b2,
                      float* __restrict__ o0, float* __restrict__ o1, float* __restrict__ o2,
                      ushort* __restrict__ aux, const float* __restrict__ seq) {
    constexpr int K = (LID == 0 || LID == 3) ? 1024 : 2048;
    const float KSCALE = 0.088388347648318447f;  // 1/sqrt(128)

    // XCD-bijective swizzle: 4 m-blocks of each n-tile land on one XCD (L2 weight reuse).
    int hwid = blockIdx.x;
    int xcd = hwid & 7;
    int q = hwid >> 3;
    int mt = q & 3;
    int g = ((q >> 2) << 3) + xcd;
    int bm = mt << 6, bn = g << 6;

    int t = threadIdx.x;
    int w = t >> 6, l = t & 63;
    int wr = w >> 1, wc = w & 1;
    int lr = l & 15, lg = l >> 4;

    // segment select (each 64-wide n-tile lies in exactly one segment)
    const float* W; const float* bias; int ns; int seg;
    if constexpr (LID == 0) {
        if (bn < 2048) { W = W0; bias = b0; ns = bn; seg = 0; }
        else           { W = W1; bias = b1; ns = bn - 2048; seg = 1; }
    } else if constexpr (LID == 1) {
        if (bn < 1024)      { W = W0; bias = b0; ns = bn; seg = 0; }
        else if (bn < 2048) { W = W1; bias = b1; ns = bn - 1024; seg = 1; }
        else                { W = W2; bias = nullptr; ns = bn - 2048; seg = 2; }
    } else if constexpr (LID == 2) {
        if (bn < 1024) { W = W0; bias = b0; ns = bn; seg = 0; }
        else           { W = W1; bias = b1; ns = bn - 1024; seg = 1; }
    } else {
        W = W0; bias = b0; ns = bn; seg = 0;
    }

    f32x4 acc00 = {}, acc01 = {}, acc10 = {}, acc11 = {};
    const ushort* Ap0 = A + (size_t)(bm + wr * 32 + lr) * K + lg * 8;
    const ushort* Ap1 = Ap0 + (size_t)16 * K;
    const float*  Wp0 = W + (size_t)(ns + wc * 32 + lr) * K + lg * 8;
    const float*  Wp1 = Wp0 + (size_t)16 * K;

    #pragma unroll 4
    for (int kk = 0; kk < K; kk += 32) {
        short8 a0 = *(const short8*)(Ap0 + kk);
        short8 a1 = *(const short8*)(Ap1 + kk);
        short8 bv0 = cvtW8(Wp0 + kk);
        short8 bv1 = cvtW8(Wp1 + kk);
        acc00 = __builtin_amdgcn_mfma_f32_16x16x32_bf16(a0, bv0, acc00, 0, 0, 0);
        acc01 = __builtin_amdgcn_mfma_f32_16x16x32_bf16(a0, bv1, acc01, 0, 0, 0);
        acc10 = __builtin_amdgcn_mfma_f32_16x16x32_bf16(a1, bv0, acc10, 0, 0, 0);
        acc11 = __builtin_amdgcn_mfma_f32_16x16x32_bf16(a1, bv1, acc11, 0, 0, 0);
    }

    f32x4 acc[2][2] = {{acc00, acc01}, {acc10, acc11}};
    #pragma unroll
    for (int i = 0; i < 2; i++) {
        #pragma unroll
        for (int j = 0; j < 2; j++) {
            int n = ns + wc * 32 + j * 16 + lr;   // segment-local col
            float bb = bias ? bias[n] : 0.f;
            #pragma unroll
            for (int r = 0; r < 4; r++) {
                int m = bm + wr * 32 + i * 16 + lg * 4 + r;
                float val = acc[i][j][r] + bb;
                if constexpr (LID == 0) {
                    if (seg == 0) {
                        o0[(size_t)m * 2048 + n] = val;           // x_t f32
                        aux[(size_t)m * 2048 + n] = f2bf(val);    // x_t bf16
                    } else {
                        o1[(size_t)m * 1024 + n] = val * sigf(val);  // silu(r_t)
                    }
                } else if constexpr (LID == 1) {
                    if (seg == 0)      o0[(size_t)m * 1024 + n] = val;           // q
                    else if (seg == 1) o1[(size_t)m * 1024 + n] = val * KSCALE;  // k/sqrt(d)
                    else               o2[(size_t)m * 1024 + n] = val;           // skip
                } else if constexpr (LID == 2) {
                    if (seg == 0) o0[(size_t)m * 1024 + n] = val;        // v
                    else          o1[(size_t)m * 1024 + n] = sigf(val);  // o gate
                } else {
                    o0[(size_t)m * 1024 + n] = val + seq[(size_t)m * 1024 + n];  // out
                }
            }
        }
    }
}

// ---------------- Causal feature conv (KER=4) + SiLU -> bf16 ----------------
__global__ void conv_silu_kernel(const float* __restrict__ x_t, const float* __restrict__ w,
                                 const float* __restrict__ cb, ushort* __restrict__ x_c) {
    int idx = blockIdx.x * 256 + threadIdx.x;  // 0..524287
    int b = idx >> 11, p = idx & 2047;
    const float* row = x_t + (size_t)b * P_;
    float acc = cb[0];
    #pragma unroll
    for (int j = 0; j < 4; j++) {
        int pp = p - 3 + j;
        if (pp >= 0) acc = fmaf(w[j], row[pp], acc);
    }
    x_c[idx] = f2bf(acc * (1.f / (1.f + expf(-acc))));
}

// ---------------- i/f gates: [256,16] dots of length 2048 (one wave each) ----------------
__global__ void gates_kernel(const ushort* __restrict__ xc,
                             const float* __restrict__ Wi, const float* __restrict__ Wf,
                             const float* __restrict__ bi, const float* __restrict__ bfp,
                             float* __restrict__ itb, float* __restrict__ ftb) {
    int w = threadIdx.x >> 6, l = threadIdx.x & 63;
    int gid = blockIdx.x * 4 + w;   // 0..4095
    int b = gid >> 4, n = gid & 15;
    const float* Wrow = (n < 8) ? (Wi + (size_t)n * 2048) : (Wf + (size_t)(n - 8) * 2048);
    const ushort* arow = xc + (size_t)b * 2048;
    float s = 0.f;
    #pragma unroll
    for (int c = 0; c < 4; c++) {
        int k0 = c * 512 + l * 8;
        short8 a = *(const short8*)(arow + k0);
        f32x4 w0 = *(const f32x4*)(Wrow + k0);
        f32x4 w1 = *(const f32x4*)(Wrow + k0 + 4);
        s = fmaf(bf2f((ushort)a[0]), w0[0], s);
        s = fmaf(bf2f((ushort)a[1]), w0[1], s);
        s = fmaf(bf2f((ushort)a[2]), w0[2], s);
        s = fmaf(bf2f((ushort)a[3]), w0[3], s);
        s = fmaf(bf2f((ushort)a[4]), w1[0], s);
        s = fmaf(bf2f((ushort)a[5]), w1[1], s);
        s = fmaf(bf2f((ushort)a[6]), w1[2], s);
        s = fmaf(bf2f((ushort)a[7]), w1[3], s);
    }
    #pragma unroll
    for (int o = 32; o; o >>= 1) s += __shfl_down(s, o, 64);
    if (l == 0) {
        if (n < 8) itb[b * 8 + n] = s + bi[n];
        else       ftb[b * 8 + (n - 8)] = s + bfp[n - 8];
    }
}

// ---------------- Fused cell: c/n/m update, q-readout, groupnorm, skip, r-gate ------
__global__ void cell_kernel(const float* __restrict__ q, const float* __restrict__ k,
                            const float* __restrict__ v, const float* __restrict__ o,
                            const float* __restrict__ i_t, const float* __restrict__ f_t,
                            const float* __restrict__ m_tm1, const float* __restrict__ n_tm1,
                            const float* __restrict__ c_tm1,
                            const float* __restrict__ gn_g, const float* __restrict__ gn_b,
                            const float* __restrict__ skip, const float* __restrict__ sr,
                            float* __restrict__ c_out, float* __restrict__ n_out,
                            float* __restrict__ m_out, ushort* __restrict__ y) {
    int bh = blockIdx.x;  // 0..2047
    int h = bh & 7;
    int t = threadIdx.x;
    __shared__ __align__(16) float qs[128];
    __shared__ __align__(16) float ks[128];
    __shared__ __align__(16) float vs[128];
    __shared__ float hnum[128];
    __shared__ float redA[4], redB[4];
    __shared__ float dsh, mu_s, rs_s;

    float fi = i_t[bh], ff = f_t[bh], mo = m_tm1[bh];
    float mt = fmaxf(ff + mo, fi);
    float ie = expf(fi - mt);
    float fe = expf(ff - mt + mo);
    if (t == 0) m_out[bh] = mt;

    int base = bh << 7;
    if (t < 128) { qs[t] = q[base + t]; ks[t] = k[base + t]; vs[t] = v[base + t]; }
    __syncthreads();

    // n_t and denominator
    float dn = 0.f;
    if (t < 128) {
        float nt = fe * n_tm1[base + t] + ie * ks[t];
        n_out[base + t] = nt;
        dn = nt * qs[t];
    }
    #pragma unroll
    for (int off2 = 32; off2; off2 >>= 1) dn += __shfl_down(dn, off2, 64);
    int wid = t >> 6, lane = t & 63;
    if (lane == 0) redA[wid] = dn;
    __syncthreads();
    if (t == 0) dsh = fmaxf(redA[0] + redA[1], 1.f);

    // c update + per-row dot with q. 8 groups of 32 lanes.
    const float* cin = c_tm1 + ((size_t)bh << 14);
    float* cout = c_out + ((size_t)bh << 14);
    int l32 = t & 31, grp = t >> 5;
    float4 k4 = *(const float4*)&ks[l32 << 2];
    float4 q4 = *(const float4*)&qs[l32 << 2];
    #pragma unroll
    for (int it2 = 0; it2 < 16; ++it2) {
        int d = (it2 << 3) + grp;
        float vd = vs[d] * ie;
        int off = (d << 7) + (l32 << 2);
        float4 c4 = *(const float4*)(cin + off);
        float4 ct;
        ct.x = fmaf(fe, c4.x, vd * k4.x);
        ct.y = fmaf(fe, c4.y, vd * k4.y);
        ct.z = fmaf(fe, c4.z, vd * k4.z);
        ct.w = fmaf(fe, c4.w, vd * k4.w);
        *(float4*)(cout + off) = ct;
        float p = ct.x * q4.x + ct.y * q4.y + ct.z * q4.z + ct.w * q4.w;
        #pragma unroll
        for (int o2 = 16; o2; o2 >>= 1) p += __shfl_xor(p, o2, 32);
        if (l32 == 0) hnum[d] = p;
    }
    __syncthreads();

    // h, groupnorm over 128, skip add, r-gate
    float hval = 0.f;
    if (t < 128) hval = o[base + t] * hnum[t] / dsh;
    float s1 = hval, s2 = hval * hval;
    #pragma unroll
    for (int off2 = 32; off2; off2 >>= 1) { s1 += __shfl_down(s1, off2, 64); s2 += __shfl_down(s2, off2, 64); }
    if (lane == 0) { redA[wid] = s1; redB[wid] = s2; }
    __syncthreads();
    if (t == 0) {
        float S1 = redA[0] + redA[1], S2 = redB[0] + redB[1];
        float mu = S1 / 128.f;
        mu_s = mu;
        rs_s = rsqrtf(S2 / 128.f - mu * mu + 1e-5f);
    }
    __syncthreads();
    if (t < 128) {
        float xn = (hval - mu_s) * rs_s;
        int gi = (h << 7) + t;
        y[base + t] = f2bf((xn * gn_g[gi] + gn_b[gi] + skip[base + t]) * sr[base + t]);
    }
}

extern "C" void kernel_launch(void* const* d_in, const int* in_sizes, int n_in,
                              void* d_out, int out_size, void* d_ws, size_t ws_size,
                              hipStream_t stream) {
    const float* seq    = (const float*)d_in[0];
    const float* c_tm1  = (const float*)d_in[1];
    const float* n_tm1  = (const float*)d_in[2];
    const float* m_tm1  = (const float*)d_in[3];
    const float* ln_g   = (const float*)d_in[4];
    const float* ln_b   = (const float*)d_in[5];
    const float* Wul    = (const float*)d_in[6];
    const float* bul    = (const float*)d_in[7];
    const float* Wur    = (const float*)d_in[8];
    const float* bur    = (const float*)d_in[9];
    const float* conv_w = (const float*)d_in[10];
    const float* conv_b = (const float*)d_in[11];
    const float* Wskip  = (const float*)d_in[12];
    const float* Wi     = (const float*)d_in[13];
    const float* bi     = (const float*)d_in[14];
    const float* Wf     = (const float*)d_in[15];
    const float* bf     = (const float*)d_in[16];
    const float* Wo     = (const float*)d_in[17];
    const float* bo     = (const float*)d_in[18];
    const float* Wq     = (const float*)d_in[19];
    const float* bq     = (const float*)d_in[20];
    const float* Wk     = (const float*)d_in[21];
    const float* bk     = (const float*)d_in[22];
    const float* Wv     = (const float*)d_in[23];
    const float* bv     = (const float*)d_in[24];
    const float* gn_g   = (const float*)d_in[25];
    const float* gn_b   = (const float*)d_in[26];
    const float* Wd     = (const float*)d_in[27];
    const float* bd     = (const float*)d_in[28];

    float* out   = (float*)d_out;          // [256,1024]
    float* c_out = out + 262144;           // [256,8,128,128]
    float* n_out = c_out + 33554432;       // [256,8,128]
    float* m_out = n_out + 262144;         // [256,8]

    float* ws    = (float*)d_ws;
    float*  x_t  = ws;                           // 524288 f32
    ushort* xnb  = (ushort*)(ws + 524288);       // 262144 bf16
    ushort* xtb  = (ushort*)(ws + 655360);       // 524288 bf16
    float*  sr   = ws + 917504;                  // 262144 f32
    ushort* xcb  = (ushort*)(ws + 1179648);      // 524288 bf16
    float*  qb   = ws + 1441792;                 // 262144
    float*  kb   = ws + 1703936;
    float*  vb   = ws + 1966080;
    float*  ob   = ws + 2228224;
    float*  skipb= ws + 2490368;
    float*  itb  = ws + 2752512;                 // 2048
    float*  ftb  = ws + 2754560;                 // 2048
    ushort* ybf  = (ushort*)(ws + 2756608);      // 262144 bf16

    dim3 blk(256);

    ln_kernel<<<256, blk, 0, stream>>>(seq, ln_g, ln_b, xnb);
    // x_n @ [Wul | Wur] : N=3072, K=1024 -> x_t (f32+bf16), silu(r_t)
    mgemm<0><<<192, blk, 0, stream>>>(xnb, Wul, Wur, nullptr, bul, bur, nullptr,
                                      x_t, sr, nullptr, xtb, nullptr);
    conv_silu_kernel<<<2048, blk, 0, stream>>>(x_t, conv_w, conv_b, xcb);
    // x_c @ [Wq | Wk | Wskip] : N=3072, K=2048 -> q, k*scale, skip
    mgemm<1><<<192, blk, 0, stream>>>(xcb, Wq, Wk, Wskip, bq, bk, nullptr,
                                      qb, kb, skipb, nullptr, nullptr);
    // x_t @ [Wv | Wo] : N=2048, K=2048 -> v, sigmoid(o)
    mgemm<2><<<128, blk, 0, stream>>>(xtb, Wv, Wo, nullptr, bv, bo, nullptr,
                                      vb, ob, nullptr, nullptr, nullptr);
    gates_kernel<<<1024, blk, 0, stream>>>(xcb, Wi, Wf, bi, bf, itb, ftb);
    cell_kernel<<<2048, blk, 0, stream>>>(qb, kb, vb, ob, itb, ftb, m_tm1, n_tm1, c_tm1,
                                          gn_g, gn_b, skipb, sr, c_out, n_out, m_out, ybf);
    // y @ Wd : N=1024, K=1024 -> out (+bd+seq)
    mgemm<3><<<64, blk, 0, stream>>>(ybf, Wd, nullptr, nullptr, bd, nullptr, nullptr,
                                     out, nullptr, nullptr, nullptr, seq);
}

// Round 6
// 410.821 us; speedup vs baseline: 5.5464x; 1.2824x over previous
//
#include <hip/hip_runtime.h>
#include <hip/hip_bf16.h>
#include <math.h>

#define B_   256
#define DIM_ 1024
#define H_   8
#define D_   128
#define P_   2048
#define HD_  1024

typedef short short8 __attribute__((ext_vector_type(8)));
typedef float f32x4 __attribute__((ext_vector_type(4)));

__device__ __forceinline__ float sigf(float x) { return 1.f / (1.f + expf(-x)); }

__device__ __forceinline__ ushort f2bf(float f) {
    return __builtin_bit_cast(unsigned short, __float2bfloat16(f));
}
__device__ __forceinline__ float bf2f(ushort u) {
    unsigned int v = ((unsigned int)u) << 16;
    return __builtin_bit_cast(float, v);
}

#define GLOAD16(gp, lp) \
    __builtin_amdgcn_global_load_lds((const __attribute__((address_space(1))) void*)(gp), \
                                     (__attribute__((address_space(3))) void*)(lp), 16, 0, 0)

// concatenated bf16 weight offsets (ushort units)
#define WOFF_UL    0
#define WOFF_UR    2097152
#define WOFF_Q     3145728
#define WOFF_K     5242880
#define WOFF_SKIP  7340032
#define WOFF_V     9437184
#define WOFF_O     11534336
#define WOFF_D     13631488
#define WOFF_END   14680064

// ---------------- Weight f32 -> bf16 conversion (runs first, no deps) ----------------
__global__ void wcvt_kernel(const float* __restrict__ s0, const float* __restrict__ s1,
                            const float* __restrict__ s2, const float* __restrict__ s3,
                            const float* __restrict__ s4, const float* __restrict__ s5,
                            const float* __restrict__ s6, const float* __restrict__ s7,
                            ushort* __restrict__ dst) {
    size_t e = ((size_t)blockIdx.x * 256 + threadIdx.x) * 8;
    const float* sp;
    if      (e < WOFF_UR)   { sp = s0 + e; }
    else if (e < WOFF_Q)    { sp = s1 + (e - WOFF_UR); }
    else if (e < WOFF_K)    { sp = s2 + (e - WOFF_Q); }
    else if (e < WOFF_SKIP) { sp = s3 + (e - WOFF_K); }
    else if (e < WOFF_V)    { sp = s4 + (e - WOFF_SKIP); }
    else if (e < WOFF_O)    { sp = s5 + (e - WOFF_V); }
    else if (e < WOFF_D)    { sp = s6 + (e - WOFF_O); }
    else                    { sp = s7 + (e - WOFF_D); }
    f32x4 a = *(const f32x4*)sp;
    f32x4 b = *(const f32x4*)(sp + 4);
    short8 r;
    r[0] = (short)f2bf(a[0]); r[1] = (short)f2bf(a[1]);
    r[2] = (short)f2bf(a[2]); r[3] = (short)f2bf(a[3]);
    r[4] = (short)f2bf(b[0]); r[5] = (short)f2bf(b[1]);
    r[6] = (short)f2bf(b[2]); r[7] = (short)f2bf(b[3]);
    *(short8*)(dst + e) = r;
}

// ---------------- LayerNorm -> bf16: one block per row of [256,1024] ----------------
__global__ void ln_kernel(const float* __restrict__ x, const float* __restrict__ g,
                          const float* __restrict__ bt, ushort* __restrict__ y) {
    int b = blockIdx.x, t = threadIdx.x;
    const float* row = x + (size_t)b * DIM_;
    float4 v = *(const float4*)(row + t * 4);
    float s1 = v.x + v.y + v.z + v.w;
    float s2 = v.x * v.x + v.y * v.y + v.z * v.z + v.w * v.w;
    #pragma unroll
    for (int o = 32; o; o >>= 1) { s1 += __shfl_down(s1, o, 64); s2 += __shfl_down(s2, o, 64); }
    __shared__ float r1[4], r2[4];
    __shared__ float mu_s, rs_s;
    int wid = t >> 6, lane = t & 63;
    if (lane == 0) { r1[wid] = s1; r2[wid] = s2; }
    __syncthreads();
    if (t == 0) {
        float S1 = r1[0] + r1[1] + r1[2] + r1[3];
        float S2 = r2[0] + r2[1] + r2[2] + r2[3];
        float mu = S1 / DIM_;
        mu_s = mu;
        rs_s = rsqrtf(S2 / DIM_ - mu * mu + 1e-5f);
    }
    __syncthreads();
    float mu = mu_s, rs = rs_s;
    float4 gg = *(const float4*)(g + t * 4);
    float4 bb = *(const float4*)(bt + t * 4);
    ushort4 o4;
    o4.x = f2bf((v.x - mu) * rs * gg.x + bb.x);
    o4.y = f2bf((v.y - mu) * rs * gg.y + bb.y);
    o4.z = f2bf((v.z - mu) * rs * gg.z + bb.z);
    o4.w = f2bf((v.w - mu) * rs * gg.w + bb.w);
    *(ushort4*)(y + (size_t)b * DIM_ + t * 4) = o4;
}

// ---------------- 2-phase LDS-staged bf16 MFMA GEMM ----------------
// C[256,N] = A_bf16[256,K] @ Wb_bf16[N,K]^T. Tile 64x64, BK=64, double-buffered LDS,
// global_load_lds(16B) staging with pre-swizzled global source; XOR-swizzled ds_read.
// 4 waves (2x2), each wave 32x32 out.
template <int GID>
__global__ void g_gemm(const ushort* __restrict__ A0, const ushort* __restrict__ A1,
                       const ushort* __restrict__ Wb,
                       const float* __restrict__ b0, const float* __restrict__ b1,
                       const float* __restrict__ b2, const float* __restrict__ b3,
                       const float* __restrict__ b4,
                       float* __restrict__ o0, float* __restrict__ o1, float* __restrict__ o2,
                       float* __restrict__ o3, float* __restrict__ o4v,
                       ushort* __restrict__ aux, const float* __restrict__ seq) {
    constexpr int K = (GID == 1) ? 2048 : 1024;
    constexpr int NT = K / 64;
    const float KSCALE = 0.088388347648318447f;  // 1/sqrt(128)

    __shared__ __align__(16) ushort As[2][64 * 64];
    __shared__ __align__(16) ushort Bs[2][64 * 64];

    // XCD-bijective swizzle: 4 m-blocks of each n-panel land on one XCD.
    int hwid = blockIdx.x;
    int xcd = hwid & 7, q = hwid >> 3;
    int mt = q & 3, g = ((q >> 2) << 3) + xcd;
    int bm = mt << 6, bn = g << 6;

    const ushort* Ab = A0;
    if constexpr (GID == 1) { if (bn >= 3072) Ab = A1; }

    int tid = threadIdx.x;
    int w = tid >> 6, l = tid & 63;
    int wr = w >> 1, wc = w & 1;
    int lr = l & 15, lg = l >> 4;

    // staging lane constants: slot si covers LDS bytes [si*16, si*16+16)
    int si0 = tid, si1 = 256 + tid;
    int r0 = si0 >> 3, su0 = (si0 & 7) ^ (r0 & 7);
    int r1 = si1 >> 3, su1 = (si1 & 7) ^ (r1 & 7);
    const ushort* gA0 = Ab + (size_t)(bm + r0) * K + su0 * 8;
    const ushort* gA1 = Ab + (size_t)(bm + r1) * K + su1 * 8;
    const ushort* gB0 = Wb + (size_t)(bn + r0) * K + su0 * 8;
    const ushort* gB1 = Wb + (size_t)(bn + r1) * K + su1 * 8;

    f32x4 acc[2][2] = {};

    GLOAD16(gA0, &As[0][si0 * 8]);
    GLOAD16(gA1, &As[0][si1 * 8]);
    GLOAD16(gB0, &Bs[0][si0 * 8]);
    GLOAD16(gB1, &Bs[0][si1 * 8]);
    __syncthreads();

    int cur = 0;
    for (int t = 0; t < NT; t++) {
        if (t + 1 < NT) {
            int k0 = (t + 1) * 64;
            int nb = cur ^ 1;
            GLOAD16(gA0 + k0, &As[nb][si0 * 8]);
            GLOAD16(gA1 + k0, &As[nb][si1 * 8]);
            GLOAD16(gB0 + k0, &Bs[nb][si0 * 8]);
            GLOAD16(gB1 + k0, &Bs[nb][si1 * 8]);
        }
        const char* Ac = (const char*)As[cur];
        const char* Bc = (const char*)Bs[cur];
        short8 af[2][2], bf_[2][2];
        #pragma unroll
        for (int mi = 0; mi < 2; mi++) {
            #pragma unroll
            for (int ks = 0; ks < 2; ks++) {
                int r = wr * 32 + mi * 16 + lr;
                int c = (ks * 64 + lg * 16) ^ ((r & 7) << 4);
                af[mi][ks] = *(const short8*)(Ac + r * 128 + c);
            }
        }
        #pragma unroll
        for (int ni = 0; ni < 2; ni++) {
            #pragma unroll
            for (int ks = 0; ks < 2; ks++) {
                int r = wc * 32 + ni * 16 + lr;
                int c = (ks * 64 + lg * 16) ^ ((r & 7) << 4);
                bf_[ni][ks] = *(const short8*)(Bc + r * 128 + c);
            }
        }
        #pragma unroll
        for (int ks = 0; ks < 2; ks++) {
            #pragma unroll
            for (int mi = 0; mi < 2; mi++) {
                #pragma unroll
                for (int ni = 0; ni < 2; ni++) {
                    acc[mi][ni] = __builtin_amdgcn_mfma_f32_16x16x32_bf16(
                        af[mi][ks], bf_[ni][ks], acc[mi][ni], 0, 0, 0);
                }
            }
        }
        __syncthreads();
        cur ^= 1;
    }

    #pragma unroll
    for (int mi = 0; mi < 2; mi++) {
        #pragma unroll
        for (int ni = 0; ni < 2; ni++) {
            int n = bn + wc * 32 + ni * 16 + lr;  // global col
            #pragma unroll
            for (int r = 0; r < 4; r++) {
                int m = bm + wr * 32 + mi * 16 + lg * 4 + r;
                float val = acc[mi][ni][r];
                if constexpr (GID == 0) {
                    if (n < 2048) {
                        val += b0[n];
                        o0[(size_t)m * 2048 + n] = val;          // x_t f32
                        aux[(size_t)m * 2048 + n] = f2bf(val);   // x_t bf16
                    } else {
                        int nc = n - 2048;
                        val += b1[nc];
                        o1[(size_t)m * 1024 + nc] = val * sigf(val);  // silu(r_t)
                    }
                } else if constexpr (GID == 1) {
                    if (n < 1024) {
                        o0[(size_t)m * 1024 + n] = val + b0[n];                    // q
                    } else if (n < 2048) {
                        int nc = n - 1024;
                        o1[(size_t)m * 1024 + nc] = (val + b1[nc]) * KSCALE;       // k/sqrt(d)
                    } else if (n < 3072) {
                        int nc = n - 2048;
                        o2[(size_t)m * 1024 + nc] = val;                           // skip
                    } else if (n < 4096) {
                        int nc = n - 3072;
                        o3[(size_t)m * 1024 + nc] = val + b3[nc];                  // v
                    } else {
                        int nc = n - 4096;
                        o4v[(size_t)m * 1024 + nc] = sigf(val + b4[nc]);           // o gate
                    }
                } else {
                    o0[(size_t)m * 1024 + n] = val + b0[n] + seq[(size_t)m * 1024 + n];  // out
                }
            }
        }
    }
}

// ---------------- Causal feature conv (KER=4) + SiLU -> bf16 ----------------
__global__ void conv_silu_kernel(const float* __restrict__ x_t, const float* __restrict__ w,
                                 const float* __restrict__ cb, ushort* __restrict__ x_c) {
    int idx = blockIdx.x * 256 + threadIdx.x;  // 0..524287
    int b = idx >> 11, p = idx & 2047;
    const float* row = x_t + (size_t)b * P_;
    float acc = cb[0];
    #pragma unroll
    for (int j = 0; j < 4; j++) {
        int pp = p - 3 + j;
        if (pp >= 0) acc = fmaf(w[j], row[pp], acc);
    }
    x_c[idx] = f2bf(acc * (1.f / (1.f + expf(-acc))));
}

// ---------------- i/f gates: [256,16] dots of length 2048 (one wave each) ----------------
__global__ void gates_kernel(const ushort* __restrict__ xc,
                             const float* __restrict__ Wi, const float* __restrict__ Wf,
                             const float* __restrict__ bi, const float* __restrict__ bfp,
                             float* __restrict__ itb, float* __restrict__ ftb) {
    int w = threadIdx.x >> 6, l = threadIdx.x & 63;
    int gid = blockIdx.x * 4 + w;   // 0..4095
    int b = gid >> 4, n = gid & 15;
    const float* Wrow = (n < 8) ? (Wi + (size_t)n * 2048) : (Wf + (size_t)(n - 8) * 2048);
    const ushort* arow = xc + (size_t)b * 2048;
    float s = 0.f;
    #pragma unroll
    for (int c = 0; c < 4; c++) {
        int k0 = c * 512 + l * 8;
        short8 a = *(const short8*)(arow + k0);
        f32x4 w0 = *(const f32x4*)(Wrow + k0);
        f32x4 w1 = *(const f32x4*)(Wrow + k0 + 4);
        s = fmaf(bf2f((ushort)a[0]), w0[0], s);
        s = fmaf(bf2f((ushort)a[1]), w0[1], s);
        s = fmaf(bf2f((ushort)a[2]), w0[2], s);
        s = fmaf(bf2f((ushort)a[3]), w0[3], s);
        s = fmaf(bf2f((ushort)a[4]), w1[0], s);
        s = fmaf(bf2f((ushort)a[5]), w1[1], s);
        s = fmaf(bf2f((ushort)a[6]), w1[2], s);
        s = fmaf(bf2f((ushort)a[7]), w1[3], s);
    }
    #pragma unroll
    for (int o = 32; o; o >>= 1) s += __shfl_down(s, o, 64);
    if (l == 0) {
        if (n < 8) itb[b * 8 + n] = s + bi[n];
        else       ftb[b * 8 + (n - 8)] = s + bfp[n - 8];
    }
}

// ---------------- Fused cell: c/n/m update, q-readout, groupnorm, skip, r-gate ------
__global__ void cell_kernel(const float* __restrict__ q, const float* __restrict__ k,
                            const float* __restrict__ v, const float* __restrict__ o,
                            const float* __restrict__ i_t, const float* __restrict__ f_t,
                            const float* __restrict__ m_tm1, const float* __restrict__ n_tm1,
                            const float* __restrict__ c_tm1,
                            const float* __restrict__ gn_g, const float* __restrict__ gn_b,
                            const float* __restrict__ skip, const float* __restrict__ sr,
                            float* __restrict__ c_out, float* __restrict__ n_out,
                            float* __restrict__ m_out, ushort* __restrict__ y) {
    int bh = blockIdx.x;  // 0..2047
    int h = bh & 7;
    int t = threadIdx.x;
    __shared__ __align__(16) float qs[128];
    __shared__ __align__(16) float ks[128];
    __shared__ __align__(16) float vs[128];
    __shared__ float hnum[128];
    __shared__ float redA[4], redB[4];
    __shared__ float dsh, mu_s, rs_s;

    float fi = i_t[bh], ff = f_t[bh], mo = m_tm1[bh];
    float mt = fmaxf(ff + mo, fi);
    float ie = expf(fi - mt);
    float fe = expf(ff - mt + mo);
    if (t == 0) m_out[bh] = mt;

    int base = bh << 7;
    if (t < 128) { qs[t] = q[base + t]; ks[t] = k[base + t]; vs[t] = v[base + t]; }
    __syncthreads();

    // n_t and denominator
    float dn = 0.f;
    if (t < 128) {
        float nt = fe * n_tm1[base + t] + ie * ks[t];
        n_out[base + t] = nt;
        dn = nt * qs[t];
    }
    #pragma unroll
    for (int off2 = 32; off2; off2 >>= 1) dn += __shfl_down(dn, off2, 64);
    int wid = t >> 6, lane = t & 63;
    if (lane == 0) redA[wid] = dn;
    __syncthreads();
    if (t == 0) dsh = fmaxf(redA[0] + redA[1], 1.f);

    // c update + per-row dot with q. 8 groups of 32 lanes.
    const float* cin = c_tm1 + ((size_t)bh << 14);
    float* cout = c_out + ((size_t)bh << 14);
    int l32 = t & 31, grp = t >> 5;
    float4 k4 = *(const float4*)&ks[l32 << 2];
    float4 q4 = *(const float4*)&qs[l32 << 2];
    #pragma unroll
    for (int it2 = 0; it2 < 16; ++it2) {
        int d = (it2 << 3) + grp;
        float vd = vs[d] * ie;
        int off = (d << 7) + (l32 << 2);
        float4 c4 = *(const float4*)(cin + off);
        float4 ct;
        ct.x = fmaf(fe, c4.x, vd * k4.x);
        ct.y = fmaf(fe, c4.y, vd * k4.y);
        ct.z = fmaf(fe, c4.z, vd * k4.z);
        ct.w = fmaf(fe, c4.w, vd * k4.w);
        *(float4*)(cout + off) = ct;
        float p = ct.x * q4.x + ct.y * q4.y + ct.z * q4.z + ct.w * q4.w;
        #pragma unroll
        for (int o2 = 16; o2; o2 >>= 1) p += __shfl_xor(p, o2, 32);
        if (l32 == 0) hnum[d] = p;
    }
    __syncthreads();

    // h, groupnorm over 128, skip add, r-gate
    float hval = 0.f;
    if (t < 128) hval = o[base + t] * hnum[t] / dsh;
    float s1 = hval, s2 = hval * hval;
    #pragma unroll
    for (int off2 = 32; off2; off2 >>= 1) { s1 += __shfl_down(s1, off2, 64); s2 += __shfl_down(s2, off2, 64); }
    if (lane == 0) { redA[wid] = s1; redB[wid] = s2; }
    __syncthreads();
    if (t == 0) {
        float S1 = redA[0] + redA[1], S2 = redB[0] + redB[1];
        float mu = S1 / 128.f;
        mu_s = mu;
        rs_s = rsqrtf(S2 / 128.f - mu * mu + 1e-5f);
    }
    __syncthreads();
    if (t < 128) {
        float xn = (hval - mu_s) * rs_s;
        int gi = (h << 7) + t;
        y[base + t] = f2bf((xn * gn_g[gi] + gn_b[gi] + skip[base + t]) * sr[base + t]);
    }
}

extern "C" void kernel_launch(void* const* d_in, const int* in_sizes, int n_in,
                              void* d_out, int out_size, void* d_ws, size_t ws_size,
                              hipStream_t stream) {
    const float* seq    = (const float*)d_in[0];
    const float* c_tm1  = (const float*)d_in[1];
    const float* n_tm1  = (const float*)d_in[2];
    const float* m_tm1  = (const float*)d_in[3];
    const float* ln_g   = (const float*)d_in[4];
    const float* ln_b   = (const float*)d_in[5];
    const float* Wul    = (const float*)d_in[6];
    const float* bul    = (const float*)d_in[7];
    const float* Wur    = (const float*)d_in[8];
    const float* bur    = (const float*)d_in[9];
    const float* conv_w = (const float*)d_in[10];
    const float* conv_b = (const float*)d_in[11];
    const float* Wskip  = (const float*)d_in[12];
    const float* Wi     = (const float*)d_in[13];
    const float* bi     = (const float*)d_in[14];
    const float* Wf     = (const float*)d_in[15];
    const float* bf     = (const float*)d_in[16];
    const float* Wo     = (const float*)d_in[17];
    const float* bo     = (const float*)d_in[18];
    const float* Wq     = (const float*)d_in[19];
    const float* bq     = (const float*)d_in[20];
    const float* Wk     = (const float*)d_in[21];
    const float* bk     = (const float*)d_in[22];
    const float* Wv     = (const float*)d_in[23];
    const float* bv     = (const float*)d_in[24];
    const float* gn_g   = (const float*)d_in[25];
    const float* gn_b   = (const float*)d_in[26];
    const float* Wd     = (const float*)d_in[27];
    const float* bd     = (const float*)d_in[28];

    float* out   = (float*)d_out;          // [256,1024]
    float* c_out = out + 262144;           // [256,8,128,128]
    float* n_out = c_out + 33554432;       // [256,8,128]
    float* m_out = n_out + 262144;         // [256,8]

    float* ws    = (float*)d_ws;
    float*  x_t  = ws;                           // 524288 f32
    ushort* xnb  = (ushort*)(ws + 524288);       // 262144 bf16
    ushort* xtb  = (ushort*)(ws + 655360);       // 524288 bf16
    float*  sr   = ws + 917504;                  // 262144 f32
    ushort* xcb  = (ushort*)(ws + 1179648);      // 524288 bf16
    float*  qb   = ws + 1441792;                 // 262144
    float*  kb   = ws + 1703936;
    float*  vb   = ws + 1966080;
    float*  ob   = ws + 2228224;
    float*  skipb= ws + 2490368;
    float*  itb  = ws + 2752512;                 // 2048
    float*  ftb  = ws + 2754560;                 // 2048
    ushort* ybf  = (ushort*)(ws + 2756608);      // 262144 bf16
    ushort* wbf  = (ushort*)(ws + 2887680);      // 14,680,064 bf16 (concat weights)

    dim3 blk(256);

    // weights -> bf16 (no deps, runs while nothing else is pending)
    wcvt_kernel<<<7168, blk, 0, stream>>>(Wul, Wur, Wq, Wk, Wskip, Wv, Wo, Wd, wbf);
    ln_kernel<<<256, blk, 0, stream>>>(seq, ln_g, ln_b, xnb);
    // x_n @ [Wul;Wur]^T : N=3072, K=1024 -> x_t (f32+bf16), silu(r_t)
    g_gemm<0><<<192, blk, 0, stream>>>(xnb, nullptr, wbf + WOFF_UL,
                                       bul, bur, nullptr, nullptr, nullptr,
                                       x_t, sr, nullptr, nullptr, nullptr, xtb, nullptr);
    conv_silu_kernel<<<2048, blk, 0, stream>>>(x_t, conv_w, conv_b, xcb);
    gates_kernel<<<1024, blk, 0, stream>>>(xcb, Wi, Wf, bi, bf, itb, ftb);
    // {x_c @ [Wq;Wk;Wskip]^T | x_t @ [Wv;Wo]^T} : N=5120, K=2048
    g_gemm<1><<<320, blk, 0, stream>>>(xcb, xtb, wbf + WOFF_Q,
                                       bq, bk, nullptr, bv, bo,
                                       qb, kb, skipb, vb, ob, nullptr, nullptr);
    cell_kernel<<<2048, blk, 0, stream>>>(qb, kb, vb, ob, itb, ftb, m_tm1, n_tm1, c_tm1,
                                          gn_g, gn_b, skipb, sr, c_out, n_out, m_out, ybf);
    // y @ Wd^T : N=1024, K=1024 -> out (+bd+seq)
    g_gemm<2><<<64, blk, 0, stream>>>(ybf, nullptr, wbf + WOFF_D,
                                      bd, nullptr, nullptr, nullptr, nullptr,
                                      out, nullptr, nullptr, nullptr, nullptr, nullptr, seq);
}

// Round 7
// 388.240 us; speedup vs baseline: 5.8690x; 1.0582x over previous
//
#include <hip/hip_runtime.h>
#include <hip/hip_bf16.h>
#include <math.h>

#define B_   256
#define DIM_ 1024
#define H_   8
#define D_   128
#define P_   2048
#define HD_  1024

typedef short short8 __attribute__((ext_vector_type(8)));
typedef float f32x4 __attribute__((ext_vector_type(4)));

__device__ __forceinline__ float sigf(float x) { return 1.f / (1.f + expf(-x)); }

__device__ __forceinline__ ushort f2bf(float f) {
    return __builtin_bit_cast(unsigned short, __float2bfloat16(f));
}
__device__ __forceinline__ float bf2f(ushort u) {
    unsigned int v = ((unsigned int)u) << 16;
    return __builtin_bit_cast(float, v);
}

#define GLOAD16(gp, lp) \
    __builtin_amdgcn_global_load_lds((const __attribute__((address_space(1))) void*)(gp), \
                                     (__attribute__((address_space(3))) void*)(lp), 16, 0, 0)

// concatenated bf16 weight offsets (ushort units)
#define WOFF_UL    0
#define WOFF_UR    2097152
#define WOFF_Q     3145728
#define WOFF_K     5242880
#define WOFF_SKIP  7340032
#define WOFF_V     9437184
#define WOFF_O     11534336
#define WOFF_D     13631488
#define WOFF_END   14680064

// ---------------- Weight f32 -> bf16 conversion (runs first, no deps) ----------------
__global__ void wcvt_kernel(const float* __restrict__ s0, const float* __restrict__ s1,
                            const float* __restrict__ s2, const float* __restrict__ s3,
                            const float* __restrict__ s4, const float* __restrict__ s5,
                            const float* __restrict__ s6, const float* __restrict__ s7,
                            ushort* __restrict__ dst) {
    size_t e = ((size_t)blockIdx.x * 256 + threadIdx.x) * 8;
    const float* sp;
    if      (e < WOFF_UR)   { sp = s0 + e; }
    else if (e < WOFF_Q)    { sp = s1 + (e - WOFF_UR); }
    else if (e < WOFF_K)    { sp = s2 + (e - WOFF_Q); }
    else if (e < WOFF_SKIP) { sp = s3 + (e - WOFF_K); }
    else if (e < WOFF_V)    { sp = s4 + (e - WOFF_SKIP); }
    else if (e < WOFF_O)    { sp = s5 + (e - WOFF_V); }
    else if (e < WOFF_D)    { sp = s6 + (e - WOFF_O); }
    else                    { sp = s7 + (e - WOFF_D); }
    f32x4 a = *(const f32x4*)sp;
    f32x4 b = *(const f32x4*)(sp + 4);
    short8 r;
    r[0] = (short)f2bf(a[0]); r[1] = (short)f2bf(a[1]);
    r[2] = (short)f2bf(a[2]); r[3] = (short)f2bf(a[3]);
    r[4] = (short)f2bf(b[0]); r[5] = (short)f2bf(b[1]);
    r[6] = (short)f2bf(b[2]); r[7] = (short)f2bf(b[3]);
    *(short8*)(dst + e) = r;
}

// ---------------- LayerNorm -> bf16: one block per row of [256,1024] ----------------
__global__ void ln_kernel(const float* __restrict__ x, const float* __restrict__ g,
                          const float* __restrict__ bt, ushort* __restrict__ y) {
    int b = blockIdx.x, t = threadIdx.x;
    const float* row = x + (size_t)b * DIM_;
    float4 v = *(const float4*)(row + t * 4);
    float s1 = v.x + v.y + v.z + v.w;
    float s2 = v.x * v.x + v.y * v.y + v.z * v.z + v.w * v.w;
    #pragma unroll
    for (int o = 32; o; o >>= 1) { s1 += __shfl_down(s1, o, 64); s2 += __shfl_down(s2, o, 64); }
    __shared__ float r1[4], r2[4];
    __shared__ float mu_s, rs_s;
    int wid = t >> 6, lane = t & 63;
    if (lane == 0) { r1[wid] = s1; r2[wid] = s2; }
    __syncthreads();
    if (t == 0) {
        float S1 = r1[0] + r1[1] + r1[2] + r1[3];
        float S2 = r2[0] + r2[1] + r2[2] + r2[3];
        float mu = S1 / DIM_;
        mu_s = mu;
        rs_s = rsqrtf(S2 / DIM_ - mu * mu + 1e-5f);
    }
    __syncthreads();
    float mu = mu_s, rs = rs_s;
    float4 gg = *(const float4*)(g + t * 4);
    float4 bb = *(const float4*)(bt + t * 4);
    ushort4 o4;
    o4.x = f2bf((v.x - mu) * rs * gg.x + bb.x);
    o4.y = f2bf((v.y - mu) * rs * gg.y + bb.y);
    o4.z = f2bf((v.z - mu) * rs * gg.z + bb.z);
    o4.w = f2bf((v.w - mu) * rs * gg.w + bb.w);
    *(ushort4*)(y + (size_t)b * DIM_ + t * 4) = o4;
}

// ---------------- Counted-vmcnt quad-buffered bf16 MFMA GEMM ----------------
// C[256,N] = A_bf16[256,K] @ Wb_bf16[N,K]^T. Tile 64x64, BK=64, 4 LDS buffers,
// depth-2 prefetch, s_waitcnt vmcnt(8/4/0) + single raw s_barrier per K-step (T4).
// 4 waves (2x2), each wave 32x32 out. XOR-swizzled staging/reads.
template <int GID>
__global__ void g_gemm(const ushort* __restrict__ A0, const ushort* __restrict__ A1,
                       const ushort* __restrict__ Wb,
                       const float* __restrict__ b0, const float* __restrict__ b1,
                       const float* __restrict__ b2, const float* __restrict__ b3,
                       const float* __restrict__ b4,
                       float* __restrict__ o0, float* __restrict__ o1, float* __restrict__ o2,
                       float* __restrict__ o3, float* __restrict__ o4v,
                       ushort* __restrict__ aux, const float* __restrict__ seq) {
    constexpr int K = (GID == 1) ? 2048 : 1024;
    constexpr int NT = K / 64;
    const float KSCALE = 0.088388347648318447f;  // 1/sqrt(128)

    __shared__ __align__(16) ushort As[4][64 * 64];
    __shared__ __align__(16) ushort Bs[4][64 * 64];

    // XCD-bijective swizzle: 4 m-blocks of each n-panel land on one XCD.
    int hwid = blockIdx.x;
    int xcd = hwid & 7, q = hwid >> 3;
    int mt = q & 3, g = ((q >> 2) << 3) + xcd;
    int bm = mt << 6, bn = g << 6;

    const ushort* Ab = A0;
    if constexpr (GID == 1) { if (bn >= 3072) Ab = A1; }

    int tid = threadIdx.x;
    int w = tid >> 6, l = tid & 63;
    int wr = w >> 1, wc = w & 1;
    int lr = l & 15, lg = l >> 4;

    // staging lane constants: slot si covers LDS bytes [si*16, si*16+16)
    int si0 = tid, si1 = 256 + tid;
    int r0 = si0 >> 3, su0 = (si0 & 7) ^ (r0 & 7);
    int r1 = si1 >> 3, su1 = (si1 & 7) ^ (r1 & 7);
    const ushort* gA0 = Ab + (size_t)(bm + r0) * K + su0 * 8;
    const ushort* gA1 = Ab + (size_t)(bm + r1) * K + su1 * 8;
    const ushort* gB0 = Wb + (size_t)(bn + r0) * K + su0 * 8;
    const ushort* gB1 = Wb + (size_t)(bn + r1) * K + su1 * 8;

    f32x4 acc[2][2] = {};

    // prologue: stage tiles 0 and 1 (8 loads outstanding per wave)
    #pragma unroll
    for (int pt = 0; pt < 2; pt++) {
        int k0 = pt * 64;
        GLOAD16(gA0 + k0, &As[pt][si0 * 8]);
        GLOAD16(gA1 + k0, &As[pt][si1 * 8]);
        GLOAD16(gB0 + k0, &Bs[pt][si0 * 8]);
        GLOAD16(gB1 + k0, &Bs[pt][si1 * 8]);
    }

    for (int t = 0; t < NT; t++) {
        if (t + 2 < NT) {
            int k0 = (t + 2) * 64;
            int nb = (t + 2) & 3;
            GLOAD16(gA0 + k0, &As[nb][si0 * 8]);
            GLOAD16(gA1 + k0, &As[nb][si1 * 8]);
            GLOAD16(gB0 + k0, &Bs[nb][si0 * 8]);
            GLOAD16(gB1 + k0, &Bs[nb][si1 * 8]);
            asm volatile("s_waitcnt vmcnt(8)" ::: "memory");
        } else if (t + 1 < NT) {
            asm volatile("s_waitcnt vmcnt(4)" ::: "memory");
        } else {
            asm volatile("s_waitcnt vmcnt(0)" ::: "memory");
        }
        __builtin_amdgcn_sched_barrier(0);
        __builtin_amdgcn_s_barrier();
        __builtin_amdgcn_sched_barrier(0);

        int cur = t & 3;
        const char* Ac = (const char*)As[cur];
        const char* Bc = (const char*)Bs[cur];
        short8 af[2][2], bf_[2][2];
        #pragma unroll
        for (int mi = 0; mi < 2; mi++) {
            #pragma unroll
            for (int ks = 0; ks < 2; ks++) {
                int r = wr * 32 + mi * 16 + lr;
                int c = (ks * 64 + lg * 16) ^ ((r & 7) << 4);
                af[mi][ks] = *(const short8*)(Ac + r * 128 + c);
            }
        }
        #pragma unroll
        for (int ni = 0; ni < 2; ni++) {
            #pragma unroll
            for (int ks = 0; ks < 2; ks++) {
                int r = wc * 32 + ni * 16 + lr;
                int c = (ks * 64 + lg * 16) ^ ((r & 7) << 4);
                bf_[ni][ks] = *(const short8*)(Bc + r * 128 + c);
            }
        }
        #pragma unroll
        for (int ks = 0; ks < 2; ks++) {
            #pragma unroll
            for (int mi = 0; mi < 2; mi++) {
                #pragma unroll
                for (int ni = 0; ni < 2; ni++) {
                    acc[mi][ni] = __builtin_amdgcn_mfma_f32_16x16x32_bf16(
                        af[mi][ks], bf_[ni][ks], acc[mi][ni], 0, 0, 0);
                }
            }
        }
        // reads of buf[cur] are complete (lgkmcnt enforced before MFMA use);
        // next DMA target (t+3)&3 != any buffer readable within skew 1.
        __builtin_amdgcn_sched_barrier(0);
    }

    #pragma unroll
    for (int mi = 0; mi < 2; mi++) {
        #pragma unroll
        for (int ni = 0; ni < 2; ni++) {
            int n = bn + wc * 32 + ni * 16 + lr;  // global col
            #pragma unroll
            for (int r = 0; r < 4; r++) {
                int m = bm + wr * 32 + mi * 16 + lg * 4 + r;
                float val = acc[mi][ni][r];
                if constexpr (GID == 0) {
                    if (n < 2048) {
                        val += b0[n];
                        o0[(size_t)m * 2048 + n] = val;          // x_t f32
                        aux[(size_t)m * 2048 + n] = f2bf(val);   // x_t bf16
                    } else {
                        int nc = n - 2048;
                        val += b1[nc];
                        o1[(size_t)m * 1024 + nc] = val * sigf(val);  // silu(r_t)
                    }
                } else if constexpr (GID == 1) {
                    if (n < 1024) {
                        o0[(size_t)m * 1024 + n] = val + b0[n];                    // q
                    } else if (n < 2048) {
                        int nc = n - 1024;
                        o1[(size_t)m * 1024 + nc] = (val + b1[nc]) * KSCALE;       // k/sqrt(d)
                    } else if (n < 3072) {
                        int nc = n - 2048;
                        o2[(size_t)m * 1024 + nc] = val;                           // skip
                    } else if (n < 4096) {
                        int nc = n - 3072;
                        o3[(size_t)m * 1024 + nc] = val + b3[nc];                  // v
                    } else {
                        int nc = n - 4096;
                        o4v[(size_t)m * 1024 + nc] = sigf(val + b4[nc]);           // o gate
                    }
                } else {
                    o0[(size_t)m * 1024 + n] = val + b0[n] + seq[(size_t)m * 1024 + n];  // out
                }
            }
        }
    }
}

// ---------------- Causal feature conv (KER=4) + SiLU -> bf16 ----------------
__global__ void conv_silu_kernel(const float* __restrict__ x_t, const float* __restrict__ w,
                                 const float* __restrict__ cb, ushort* __restrict__ x_c) {
    int idx = blockIdx.x * 256 + threadIdx.x;  // 0..524287
    int b = idx >> 11, p = idx & 2047;
    const float* row = x_t + (size_t)b * P_;
    float acc = cb[0];
    #pragma unroll
    for (int j = 0; j < 4; j++) {
        int pp = p - 3 + j;
        if (pp >= 0) acc = fmaf(w[j], row[pp], acc);
    }
    x_c[idx] = f2bf(acc * (1.f / (1.f + expf(-acc))));
}

// ---------------- i/f gates: [256,16] dots of length 2048 (one wave each) ----------------
__global__ void gates_kernel(const ushort* __restrict__ xc,
                             const float* __restrict__ Wi, const float* __restrict__ Wf,
                             const float* __restrict__ bi, const float* __restrict__ bfp,
                             float* __restrict__ itb, float* __restrict__ ftb) {
    int w = threadIdx.x >> 6, l = threadIdx.x & 63;
    int gid = blockIdx.x * 4 + w;   // 0..4095
    int b = gid >> 4, n = gid & 15;
    const float* Wrow = (n < 8) ? (Wi + (size_t)n * 2048) : (Wf + (size_t)(n - 8) * 2048);
    const ushort* arow = xc + (size_t)b * 2048;
    float s = 0.f;
    #pragma unroll
    for (int c = 0; c < 4; c++) {
        int k0 = c * 512 + l * 8;
        short8 a = *(const short8*)(arow + k0);
        f32x4 w0 = *(const f32x4*)(Wrow + k0);
        f32x4 w1 = *(const f32x4*)(Wrow + k0 + 4);
        s = fmaf(bf2f((ushort)a[0]), w0[0], s);
        s = fmaf(bf2f((ushort)a[1]), w0[1], s);
        s = fmaf(bf2f((ushort)a[2]), w0[2], s);
        s = fmaf(bf2f((ushort)a[3]), w0[3], s);
        s = fmaf(bf2f((ushort)a[4]), w1[0], s);
        s = fmaf(bf2f((ushort)a[5]), w1[1], s);
        s = fmaf(bf2f((ushort)a[6]), w1[2], s);
        s = fmaf(bf2f((ushort)a[7]), w1[3], s);
    }
    #pragma unroll
    for (int o = 32; o; o >>= 1) s += __shfl_down(s, o, 64);
    if (l == 0) {
        if (n < 8) itb[b * 8 + n] = s + bi[n];
        else       ftb[b * 8 + (n - 8)] = s + bfp[n - 8];
    }
}

// ---------------- Fused cell: c/n/m update, q-readout, groupnorm, skip, r-gate ------
__global__ void cell_kernel(const float* __restrict__ q, const float* __restrict__ k,
                            const float* __restrict__ v, const float* __restrict__ o,
                            const float* __restrict__ i_t, const float* __restrict__ f_t,
                            const float* __restrict__ m_tm1, const float* __restrict__ n_tm1,
                            const float* __restrict__ c_tm1,
                            const float* __restrict__ gn_g, const float* __restrict__ gn_b,
                            const float* __restrict__ skip, const float* __restrict__ sr,
                            float* __restrict__ c_out, float* __restrict__ n_out,
                            float* __restrict__ m_out, ushort* __restrict__ y) {
    int bh = blockIdx.x;  // 0..2047
    int h = bh & 7;
    int t = threadIdx.x;
    __shared__ __align__(16) float qs[128];
    __shared__ __align__(16) float ks[128];
    __shared__ __align__(16) float vs[128];
    __shared__ float hnum[128];
    __shared__ float redA[4], redB[4];
    __shared__ float dsh, mu_s, rs_s;

    float fi = i_t[bh], ff = f_t[bh], mo = m_tm1[bh];
    float mt = fmaxf(ff + mo, fi);
    float ie = expf(fi - mt);
    float fe = expf(ff - mt + mo);
    if (t == 0) m_out[bh] = mt;

    int base = bh << 7;
    if (t < 128) { qs[t] = q[base + t]; ks[t] = k[base + t]; vs[t] = v[base + t]; }
    __syncthreads();

    // n_t and denominator
    float dn = 0.f;
    if (t < 128) {
        float nt = fe * n_tm1[base + t] + ie * ks[t];
        n_out[base + t] = nt;
        dn = nt * qs[t];
    }
    #pragma unroll
    for (int off2 = 32; off2; off2 >>= 1) dn += __shfl_down(dn, off2, 64);
    int wid = t >> 6, lane = t & 63;
    if (lane == 0) redA[wid] = dn;
    __syncthreads();
    if (t == 0) dsh = fmaxf(redA[0] + redA[1], 1.f);

    // c update + per-row dot with q. 8 groups of 32 lanes.
    const float* cin = c_tm1 + ((size_t)bh << 14);
    float* cout = c_out + ((size_t)bh << 14);
    int l32 = t & 31, grp = t >> 5;
    float4 k4 = *(const float4*)&ks[l32 << 2];
    float4 q4 = *(const float4*)&qs[l32 << 2];
    #pragma unroll
    for (int it2 = 0; it2 < 16; ++it2) {
        int d = (it2 << 3) + grp;
        float vd = vs[d] * ie;
        int off = (d << 7) + (l32 << 2);
        float4 c4 = *(const float4*)(cin + off);
        float4 ct;
        ct.x = fmaf(fe, c4.x, vd * k4.x);
        ct.y = fmaf(fe, c4.y, vd * k4.y);
        ct.z = fmaf(fe, c4.z, vd * k4.z);
        ct.w = fmaf(fe, c4.w, vd * k4.w);
        *(float4*)(cout + off) = ct;
        float p = ct.x * q4.x + ct.y * q4.y + ct.z * q4.z + ct.w * q4.w;
        #pragma unroll
        for (int o2 = 16; o2; o2 >>= 1) p += __shfl_xor(p, o2, 32);
        if (l32 == 0) hnum[d] = p;
    }
    __syncthreads();

    // h, groupnorm over 128, skip add, r-gate
    float hval = 0.f;
    if (t < 128) hval = o[base + t] * hnum[t] / dsh;
    float s1 = hval, s2 = hval * hval;
    #pragma unroll
    for (int off2 = 32; off2; off2 >>= 1) { s1 += __shfl_down(s1, off2, 64); s2 += __shfl_down(s2, off2, 64); }
    if (lane == 0) { redA[wid] = s1; redB[wid] = s2; }
    __syncthreads();
    if (t == 0) {
        float S1 = redA[0] + redA[1], S2 = redB[0] + redB[1];
        float mu = S1 / 128.f;
        mu_s = mu;
        rs_s = rsqrtf(S2 / 128.f - mu * mu + 1e-5f);
    }
    __syncthreads();
    if (t < 128) {
        float xn = (hval - mu_s) * rs_s;
        int gi = (h << 7) + t;
        y[base + t] = f2bf((xn * gn_g[gi] + gn_b[gi] + skip[base + t]) * sr[base + t]);
    }
}

extern "C" void kernel_launch(void* const* d_in, const int* in_sizes, int n_in,
                              void* d_out, int out_size, void* d_ws, size_t ws_size,
                              hipStream_t stream) {
    const float* seq    = (const float*)d_in[0];
    const float* c_tm1  = (const float*)d_in[1];
    const float* n_tm1  = (const float*)d_in[2];
    const float* m_tm1  = (const float*)d_in[3];
    const float* ln_g   = (const float*)d_in[4];
    const float* ln_b   = (const float*)d_in[5];
    const float* Wul    = (const float*)d_in[6];
    const float* bul    = (const float*)d_in[7];
    const float* Wur    = (const float*)d_in[8];
    const float* bur    = (const float*)d_in[9];
    const float* conv_w = (const float*)d_in[10];
    const float* conv_b = (const float*)d_in[11];
    const float* Wskip  = (const float*)d_in[12];
    const float* Wi     = (const float*)d_in[13];
    const float* bi     = (const float*)d_in[14];
    const float* Wf     = (const float*)d_in[15];
    const float* bf     = (const float*)d_in[16];
    const float* Wo     = (const float*)d_in[17];
    const float* bo     = (const float*)d_in[18];
    const float* Wq     = (const float*)d_in[19];
    const float* bq     = (const float*)d_in[20];
    const float* Wk     = (const float*)d_in[21];
    const float* bk     = (const float*)d_in[22];
    const float* Wv     = (const float*)d_in[23];
    const float* bv     = (const float*)d_in[24];
    const float* gn_g   = (const float*)d_in[25];
    const float* gn_b   = (const float*)d_in[26];
    const float* Wd     = (const float*)d_in[27];
    const float* bd     = (const float*)d_in[28];

    float* out   = (float*)d_out;          // [256,1024]
    float* c_out = out + 262144;           // [256,8,128,128]
    float* n_out = c_out + 33554432;       // [256,8,128]
    float* m_out = n_out + 262144;         // [256,8]

    float* ws    = (float*)d_ws;
    float*  x_t  = ws;                           // 524288 f32
    ushort* xnb  = (ushort*)(ws + 524288);       // 262144 bf16
    ushort* xtb  = (ushort*)(ws + 655360);       // 524288 bf16
    float*  sr   = ws + 917504;                  // 262144 f32
    ushort* xcb  = (ushort*)(ws + 1179648);      // 524288 bf16
    float*  qb   = ws + 1441792;                 // 262144
    float*  kb   = ws + 1703936;
    float*  vb   = ws + 1966080;
    float*  ob   = ws + 2228224;
    float*  skipb= ws + 2490368;
    float*  itb  = ws + 2752512;                 // 2048
    float*  ftb  = ws + 2754560;                 // 2048
    ushort* ybf  = (ushort*)(ws + 2756608);      // 262144 bf16
    ushort* wbf  = (ushort*)(ws + 2887680);      // 14,680,064 bf16 (concat weights)

    dim3 blk(256);

    // weights -> bf16 (no deps, runs while nothing else is pending)
    wcvt_kernel<<<7168, blk, 0, stream>>>(Wul, Wur, Wq, Wk, Wskip, Wv, Wo, Wd, wbf);
    ln_kernel<<<256, blk, 0, stream>>>(seq, ln_g, ln_b, xnb);
    // x_n @ [Wul;Wur]^T : N=3072, K=1024 -> x_t (f32+bf16), silu(r_t)
    g_gemm<0><<<192, blk, 0, stream>>>(xnb, nullptr, wbf + WOFF_UL,
                                       bul, bur, nullptr, nullptr, nullptr,
                                       x_t, sr, nullptr, nullptr, nullptr, xtb, nullptr);
    conv_silu_kernel<<<2048, blk, 0, stream>>>(x_t, conv_w, conv_b, xcb);
    gates_kernel<<<1024, blk, 0, stream>>>(xcb, Wi, Wf, bi, bf, itb, ftb);
    // {x_c @ [Wq;Wk;Wskip]^T | x_t @ [Wv;Wo]^T} : N=5120, K=2048
    g_gemm<1><<<320, blk, 0, stream>>>(xcb, xtb, wbf + WOFF_Q,
                                       bq, bk, nullptr, bv, bo,
                                       qb, kb, skipb, vb, ob, nullptr, nullptr);
    cell_kernel<<<2048, blk, 0, stream>>>(qb, kb, vb, ob, itb, ftb, m_tm1, n_tm1, c_tm1,
                                          gn_g, gn_b, skipb, sr, c_out, n_out, m_out, ybf);
    // y @ Wd^T : N=1024, K=1024 -> out (+bd+seq)
    g_gemm<2><<<64, blk, 0, stream>>>(ybf, nullptr, wbf + WOFF_D,
                                      bd, nullptr, nullptr, nullptr, nullptr,
                                      out, nullptr, nullptr, nullptr, nullptr, nullptr, seq);
}